// Round 10
// baseline (127.283 us; speedup 1.0000x reference)
//
#include <hip/hip_runtime.h>

// SupConLoss on MI355X. features: [4096, 2, 128] fp32; labels: [4096] int; out: 1 f32.
//
// R9 changes vs R8:
//  - k_negsum: barrier-free / LDS-free. R8 post-mortem: every staged+barrier
//    variant lands ~41 us regardless of FLOP/atomic/LDS detail -> structural
//    vmcnt(0)+barrier stall. New design: neg_sum[j] computed as COLUMN sum
//    (matrix+mask symmetric). Wave owns 64 cols, B-frags pinned in 64 VGPRs
//    for the whole kernel; A streamed 16 rows/chunk direct from global
//    (L2-resident); col-sums in 4 regs/lane; quad-shuffle + atomic tail.
//    Grid 32 col-blocks x 32 row-segments = 1024 blocks, 4 waves each.
//  - k_normalize (fused bucket) and k_loss unchanged (verified).
//
// ws layout: nf (2 MB) | neg_sum 8192 f32 | total f32 | done u32 | counts 100
//            | offsets 101 | classIdx 4096

#define BATCH 4096
#define NN    8192
#define DD    128
#define NCLS  100
#define MAXR  192
#define SCALE (1.0f / 0.07f)

typedef __attribute__((ext_vector_type(8))) short bf16x8;
typedef __attribute__((ext_vector_type(4))) float f32x4;

__device__ __forceinline__ unsigned short f2bf(float f) {
    unsigned u = __float_as_uint(f);
    u += 0x7FFF + ((u >> 16) & 1);
    return (unsigned short)(u >> 16);
}

// normalize + zero accumulators; block 0 additionally does class bucketing
__global__ __launch_bounds__(256) void k_normalize(
        const float* __restrict__ feat, unsigned short* __restrict__ nf,
        float* __restrict__ zeroReg, const int* __restrict__ labels,
        int* __restrict__ counts, int* __restrict__ offsets,
        int* __restrict__ classIdx) {
    int gi = blockIdx.x * 256 + threadIdx.x;
    if (gi < NN + 2) zeroReg[gi] = 0.0f;
    int wave = threadIdx.x >> 6, lane = threadIdx.x & 63;
    int row = blockIdx.x * 4 + wave;
    int v = row >> 12, b = row & (BATCH - 1);
    const float2* src = (const float2*)(feat + ((size_t)b * 2 + v) * DD);
    float2 x = src[lane];
    float ss = x.x * x.x + x.y * x.y;
    #pragma unroll
    for (int m = 32; m >= 1; m >>= 1) ss += __shfl_xor(ss, m, 64);
    float inv = rsqrtf(ss);
    ushort2 o;
    o.x = f2bf(x.x * inv);
    o.y = f2bf(x.y * inv);
    ((ushort2*)(nf + (size_t)row * DD))[lane] = o;

    if (blockIdx.x == 0) {   // fused bucketing (independent of other blocks)
        __shared__ int cnt[NCLS], off[NCLS], cur[NCLS];
        int tid = threadIdx.x;
        for (int c = tid; c < NCLS; c += 256) cnt[c] = 0;
        __syncthreads();
        for (int bb = tid; bb < BATCH; bb += 256) atomicAdd(&cnt[labels[bb]], 1);
        __syncthreads();
        if (tid == 0) {
            int a = 0;
            for (int c = 0; c < NCLS; ++c) { off[c] = a; a += cnt[c]; }
        }
        __syncthreads();
        for (int c = tid; c < NCLS; c += 256) {
            cur[c] = 0;
            counts[c] = cnt[c];
            offsets[c] = off[c];
        }
        if (tid == 0) offsets[NCLS] = BATCH;
        __syncthreads();
        for (int bb = tid; bb < BATCH; bb += 256) {
            int l = labels[bb];
            int p = atomicAdd(&cur[l], 1);
            classIdx[off[l] + p] = bb;
        }
    }
}

// ---- pass 1: neg_sum[j] = sum_i exp(logit_ij) [lab(i)!=lab(j)]  (column sums;
//      matrix and mask are symmetric, so col sum == the row sum we need).
// Barrier-free, LDS-free: wave owns 64 cols (B-frags in 64 VGPRs, loaded once),
// streams 256 rows (16-row chunks) direct from global. Col sums in registers.
__global__ __launch_bounds__(256, 4) void k_negsum(
        const unsigned short* __restrict__ nf,
        const int* __restrict__ labels,
        float* __restrict__ neg_sum) {
    int tid = threadIdx.x, wave = tid >> 6, lane = tid & 63;
    int q = lane >> 4, nq = lane & 15;
    int colW = blockIdx.x * 256 + wave * 64;     // wave's 64 columns
    int rowSeg = blockIdx.y * 256;               // this block's 256 rows
    const bf16x8* nfv = (const bf16x8*)nf;

    // B fragments for 64 cols, full K=128: 16 x bf16x8 (64 VGPRs), once.
    // B-operand layout (16x16x32): lane holds B[k=(lane>>4)*8+j][n=lane&15].
    bf16x8 bF[4][4];
    #pragma unroll
    for (int cs = 0; cs < 4; ++cs) {
        int col = colW + cs * 16 + nq;
        #pragma unroll
        for (int s = 0; s < 4; ++s) bF[cs][s] = nfv[col * 16 + s * 4 + q];
    }
    int cl[4];
    #pragma unroll
    for (int cs = 0; cs < 4; ++cs) cl[cs] = labels[(colW + cs * 16 + nq) & (BATCH - 1)];
    float colsum[4] = {0.f, 0.f, 0.f, 0.f};

    #pragma unroll 2
    for (int c = 0; c < 16; ++c) {
        int row0 = rowSeg + c * 16;
        // A frags for 16 rows (layout: lane holds A[m=lane&15][k=(lane>>4)*8+j])
        bf16x8 aF[4];
        #pragma unroll
        for (int s = 0; s < 4; ++s) aF[s] = nfv[(row0 + nq) * 16 + s * 4 + q];
        int rlab[4];
        #pragma unroll
        for (int rr = 0; rr < 4; ++rr)
            rlab[rr] = labels[(row0 + q * 4 + rr) & (BATCH - 1)];

        f32x4 acc[4];
        #pragma unroll
        for (int cs = 0; cs < 4; ++cs) acc[cs] = (f32x4){0.f, 0.f, 0.f, 0.f};
        #pragma unroll
        for (int s = 0; s < 4; ++s)
            #pragma unroll
            for (int cs = 0; cs < 4; ++cs)
                acc[cs] = __builtin_amdgcn_mfma_f32_16x16x32_bf16(
                    aF[s], bF[cs][s], acc[cs], 0, 0, 0);

        // C/D layout: col = lane&15 (nq), row = q*4 + rr
        #pragma unroll
        for (int cs = 0; cs < 4; ++cs)
            #pragma unroll
            for (int rr = 0; rr < 4; ++rr) {
                float e = __expf(acc[cs][rr] * SCALE);
                colsum[cs] += (rlab[rr] != cl[cs]) ? e : 0.0f;
            }
    }

    // reduce over the 4 q-groups (lanes nq, 16+nq, 32+nq, 48+nq), then atomic
    #pragma unroll
    for (int cs = 0; cs < 4; ++cs) {
        float v = colsum[cs];
        v += __shfl_xor(v, 16, 64);
        v += __shfl_xor(v, 32, 64);
        if (q == 0) atomicAdd(&neg_sum[colW + cs * 16 + nq], v);
    }
}

// ---- pass 2: per-class MFMA over member rows + fused finalize ----
__global__ __launch_bounds__(256) void k_loss(
        const unsigned short* __restrict__ nf,
        const int* __restrict__ counts, const int* __restrict__ offsets,
        const int* __restrict__ classIdx,
        const float* __restrict__ neg_sum,
        float* __restrict__ total, unsigned* __restrict__ done,
        float* __restrict__ out) {
    __shared__ __attribute__((aligned(16))) unsigned short s_feat[MAXR * 128]; // 48 KB
    __shared__ int s_rows[MAXR];
    __shared__ float s_ns[MAXR];
    __shared__ float red[4];

    int c = blockIdx.x;
    int m = counts[c], off = offsets[c];
    int twoM = 2 * m; if (twoM > MAXR) twoM = MAXR;
    int tid = threadIdx.x, wave = tid >> 6, lane = tid & 63;
    int q = lane >> 4, nq = lane & 15;

    for (int r = tid; r < twoM; r += 256) {
        int b = classIdx[off + (r < m ? r : r - m)];
        int row = (r < m) ? b : b + BATCH;
        s_rows[r] = row;
        s_ns[r] = neg_sum[row];
    }
    __syncthreads();

    int ntile = (twoM + 63) >> 6;            // 1..3
    int nchunk = ntile * 64 * 16;
    for (int widx = wave; widx * 64 < nchunk; widx += 4) {
        int chunkIdx = widx * 64 + lane;
        int r = chunkIdx >> 4, cS = chunkIdx & 15;
        int cG = cS ^ (r & 15);
        int rc = r < twoM ? r : twoM - 1;
        const unsigned short* gp = nf + (size_t)s_rows[rc] * DD + cG * 8;
        unsigned short* lp = s_feat + (size_t)widx * 512;
        __builtin_amdgcn_global_load_lds(
            (const __attribute__((address_space(1))) void*)gp,
            (__attribute__((address_space(3))) void*)lp, 16, 0, 0);
    }
    __syncthreads();

    const char* sB = (const char*)s_feat;
    float partial = 0.0f;
    int npairs = ntile * ntile;
    for (int pp = wave; pp < npairs; pp += 4) {
        int ti = pp / ntile, tj = pp - ti * ntile;
        bf16x8 aF[4][4];
        #pragma unroll
        for (int rs = 0; rs < 4; ++rs) {
            int rA = ti * 64 + rs * 16 + nq;
            #pragma unroll
            for (int s = 0; s < 4; ++s) {
                int slot = rA * 16 + ((s * 4 + q) ^ nq);
                aF[rs][s] = *(const bf16x8*)(sB + slot * 16);
            }
        }
        f32x4 acc[4][4];
        #pragma unroll
        for (int rs = 0; rs < 4; ++rs)
            #pragma unroll
            for (int cs = 0; cs < 4; ++cs) acc[rs][cs] = (f32x4){0.f, 0.f, 0.f, 0.f};
        #pragma unroll
        for (int s = 0; s < 4; ++s) {
            bf16x8 bF[4];
            #pragma unroll
            for (int cs = 0; cs < 4; ++cs) {
                int rB = tj * 64 + cs * 16 + nq;
                int slot = rB * 16 + ((s * 4 + q) ^ nq);
                bF[cs] = *(const bf16x8*)(sB + slot * 16);
            }
            #pragma unroll
            for (int rs = 0; rs < 4; ++rs)
                #pragma unroll
                for (int cs = 0; cs < 4; ++cs)
                    acc[rs][cs] = __builtin_amdgcn_mfma_f32_16x16x32_bf16(
                        aF[rs][s], bF[cs], acc[rs][cs], 0, 0, 0);
        }
        #pragma unroll
        for (int cs = 0; cs < 4; ++cs) {
            int qq = tj * 64 + cs * 16 + nq;
            float ns = s_ns[qq < twoM ? qq : 0];
            #pragma unroll
            for (int rs = 0; rs < 4; ++rs)
                #pragma unroll
                for (int rr = 0; rr < 4; ++rr) {
                    int p = ti * 64 + rs * 16 + q * 4 + rr;
                    bool valid = (p < twoM) && (qq < twoM) && (p != qq);
                    float logit = acc[rs][cs][rr] * SCALE;
                    float term = logit - __logf(ns + __expf(logit));
                    partial += valid ? term : 0.0f;
                }
        }
    }
    #pragma unroll
    for (int mm = 32; mm >= 1; mm >>= 1) partial += __shfl_xor(partial, mm, 64);
    if (lane == 0) red[wave] = partial;
    __syncthreads();
    if (tid == 0) {
        atomicAdd(total, red[0] + red[1] + red[2] + red[3]);
        __threadfence();
        unsigned prev = __hip_atomic_fetch_add(done, 1u, __ATOMIC_ACQ_REL,
                                               __HIP_MEMORY_SCOPE_AGENT);
        if (prev == (unsigned)(NCLS - 1)) {
            float tot = __hip_atomic_load(total, __ATOMIC_ACQUIRE,
                                          __HIP_MEMORY_SCOPE_AGENT);
            out[0] = -tot * (1.0f / (float)NN);
        }
    }
}

extern "C" void kernel_launch(void* const* d_in, const int* in_sizes, int n_in,
                              void* d_out, int out_size, void* d_ws, size_t ws_size,
                              hipStream_t stream) {
    const float* feat = (const float*)d_in[0];
    const int* labels = (const int*)d_in[1];
    unsigned short* nf = (unsigned short*)d_ws;
    float* neg_sum = (float*)((char*)d_ws + (size_t)NN * DD * sizeof(unsigned short));
    float* total    = neg_sum + NN;           // 1
    unsigned* done  = (unsigned*)(total + 1); // 1
    int* counts     = (int*)(done + 1);       // 100
    int* offsets    = counts + NCLS;          // 101
    int* classIdx   = offsets + NCLS + 1;     // 4096
    float* out = (float*)d_out;

    hipLaunchKernelGGL(k_normalize, dim3(NN / 4), dim3(256), 0, stream,
                       feat, nf, neg_sum, labels, counts, offsets, classIdx);
    hipLaunchKernelGGL(k_negsum, dim3(32, 32), dim3(256), 0, stream, nf, labels, neg_sum);
    hipLaunchKernelGGL(k_loss, dim3(NCLS), dim3(256), 0, stream,
                       nf, counts, offsets, classIdx, neg_sum, total, done, out);
}

// Round 11
// 105.396 us; speedup vs baseline: 1.2077x; 1.2077x over previous
//
#include <hip/hip_runtime.h>

// SupConLoss on MI355X. features: [4096, 2, 128] fp32; labels: [4096] int; out: 1 f32.
//
// R10 changes vs R9:
//  - ROOT CAUSE of the 40-60us negsum plateau identified: MFMA fragment loads
//    from global are 16-way scattered (64 cache lines per wave load). Fix:
//    k_normalize additionally writes nfA, a FRAGMENT-MAJOR permuted copy
//    (per 16-row group: [s][lane][16B]) so frag loads are lane-consecutive
//    (1 KB/instruction, ideal coalescing). A-frag and B-frag patterns are
//    identical for a Gram matrix, so one layout serves both.
//  - Row-label mask loads: one int4 per quad (4 broadcast addrs/wave) instead
//    of 4 scattered dwords.
//  - negsum structure = R9 (barrier-free, LDS-free, col-sums in regs,
//    1 atomic/col/block). k_loss unchanged (verified).
//
// ws layout: nf (2 MB) | nfA (2 MB) | neg_sum 8192 f32 | total f32 | done u32
//            | counts 100 | offsets 101 | classIdx 4096

#define BATCH 4096
#define NN    8192
#define DD    128
#define NCLS  100
#define MAXR  192
#define SCALE (1.0f / 0.07f)

typedef __attribute__((ext_vector_type(8))) short bf16x8;
typedef __attribute__((ext_vector_type(4))) float f32x4;

__device__ __forceinline__ unsigned short f2bf(float f) {
    unsigned u = __float_as_uint(f);
    u += 0x7FFF + ((u >> 16) & 1);
    return (unsigned short)(u >> 16);
}

// normalize -> nf (row-major) + nfA (fragment-major); zero accumulators;
// block 0 additionally does class bucketing.
// nfA layout: group g = row>>4 owns 4 KB; short index for (row,k):
//   g*2048 + (k>>5)*512 + (((k>>3)&3)*16 + (row&15))*8 + (k&7)
__global__ __launch_bounds__(256) void k_normalize(
        const float* __restrict__ feat, unsigned short* __restrict__ nf,
        unsigned short* __restrict__ nfA,
        float* __restrict__ zeroReg, const int* __restrict__ labels,
        int* __restrict__ counts, int* __restrict__ offsets,
        int* __restrict__ classIdx) {
    int gi = blockIdx.x * 256 + threadIdx.x;
    if (gi < NN + 2) zeroReg[gi] = 0.0f;
    int wave = threadIdx.x >> 6, lane = threadIdx.x & 63;
    int row = blockIdx.x * 4 + wave;
    int v = row >> 12, b = row & (BATCH - 1);
    const float2* src = (const float2*)(feat + ((size_t)b * 2 + v) * DD);
    float2 x = src[lane];
    float ss = x.x * x.x + x.y * x.y;
    #pragma unroll
    for (int m = 32; m >= 1; m >>= 1) ss += __shfl_xor(ss, m, 64);
    float inv = rsqrtf(ss);
    ushort2 o;
    o.x = f2bf(x.x * inv);
    o.y = f2bf(x.y * inv);
    ((ushort2*)(nf + (size_t)row * DD))[lane] = o;
    // fragment-major copy: lane l holds k = 2l, 2l+1
    {
        int g = row >> 4, rlo = row & 15;
        int s = lane >> 4, q = (lane >> 2) & 3, off = 2 * (lane & 3);
        ((ushort2*)(nfA + (size_t)g * 2048 + s * 512 + (q * 16 + rlo) * 8 + off))[0] = o;
    }

    if (blockIdx.x == 0) {   // fused bucketing
        __shared__ int cnt[NCLS], off2[NCLS], cur[NCLS];
        int tid = threadIdx.x;
        for (int c = tid; c < NCLS; c += 256) cnt[c] = 0;
        __syncthreads();
        for (int bb = tid; bb < BATCH; bb += 256) atomicAdd(&cnt[labels[bb]], 1);
        __syncthreads();
        if (tid == 0) {
            int a = 0;
            for (int c = 0; c < NCLS; ++c) { off2[c] = a; a += cnt[c]; }
        }
        __syncthreads();
        for (int c = tid; c < NCLS; c += 256) {
            cur[c] = 0;
            counts[c] = cnt[c];
            offsets[c] = off2[c];
        }
        if (tid == 0) offsets[NCLS] = BATCH;
        __syncthreads();
        for (int bb = tid; bb < BATCH; bb += 256) {
            int l = labels[bb];
            int p = atomicAdd(&cur[l], 1);
            classIdx[off2[l] + p] = bb;
        }
    }
}

// ---- pass 1: neg_sum[j] = sum_i exp(logit_ij)[lab(i)!=lab(j)] (column sums).
// Barrier-free, LDS-free. Wave owns 64 cols (B-frags pinned, coalesced loads
// from nfA); streams 256 rows in 16-row chunks (coalesced A-frag loads).
__global__ __launch_bounds__(256, 4) void k_negsum(
        const unsigned short* __restrict__ nfA,
        const int* __restrict__ labels,
        float* __restrict__ neg_sum) {
    int tid = threadIdx.x, wave = tid >> 6, lane = tid & 63;
    int q = lane >> 4, nq = lane & 15;
    int colW = blockIdx.x * 256 + wave * 64;     // wave's 64 columns
    int rowSeg = blockIdx.y * 256;               // this block's 256 rows
    const bf16x8* nfAv = (const bf16x8*)nfA;     // 16B units; group stride 256
    const int4* lab4 = (const int4*)labels;

    // B frags: 16 coalesced 1KB loads, pinned in 64 VGPRs
    bf16x8 bF[4][4];
    #pragma unroll
    for (int cs = 0; cs < 4; ++cs) {
        int gc = (colW >> 4) + cs;
        #pragma unroll
        for (int s = 0; s < 4; ++s) bF[cs][s] = nfAv[gc * 256 + s * 64 + lane];
    }
    int cl[4];
    #pragma unroll
    for (int cs = 0; cs < 4; ++cs) cl[cs] = labels[(colW + cs * 16 + nq) & (BATCH - 1)];
    float colsum[4] = {0.f, 0.f, 0.f, 0.f};

    #pragma unroll 2
    for (int c = 0; c < 16; ++c) {
        int row0 = rowSeg + c * 16;
        int g = row0 >> 4;
        bf16x8 aF[4];
        #pragma unroll
        for (int s = 0; s < 4; ++s) aF[s] = nfAv[g * 256 + s * 64 + lane];
        int4 rl4 = lab4[((row0 & (BATCH - 1)) >> 2) + q];   // labels for rows q*4..q*4+3

        f32x4 acc[4];
        #pragma unroll
        for (int cs = 0; cs < 4; ++cs) acc[cs] = (f32x4){0.f, 0.f, 0.f, 0.f};
        #pragma unroll
        for (int s = 0; s < 4; ++s)
            #pragma unroll
            for (int cs = 0; cs < 4; ++cs)
                acc[cs] = __builtin_amdgcn_mfma_f32_16x16x32_bf16(
                    aF[s], bF[cs][s], acc[cs], 0, 0, 0);

        const int* rl = (const int*)&rl4;
        // C/D layout: col = lane&15 (nq), row = q*4 + rr
        #pragma unroll
        for (int cs = 0; cs < 4; ++cs)
            #pragma unroll
            for (int rr = 0; rr < 4; ++rr) {
                float e = __expf(acc[cs][rr] * SCALE);
                colsum[cs] += (rl[rr] != cl[cs]) ? e : 0.0f;
            }
    }

    #pragma unroll
    for (int cs = 0; cs < 4; ++cs) {
        float v = colsum[cs];
        v += __shfl_xor(v, 16, 64);
        v += __shfl_xor(v, 32, 64);
        if (q == 0) atomicAdd(&neg_sum[colW + cs * 16 + nq], v);
    }
}

// ---- pass 2: per-class MFMA over member rows + fused finalize (row-major nf) ----
__global__ __launch_bounds__(256) void k_loss(
        const unsigned short* __restrict__ nf,
        const int* __restrict__ counts, const int* __restrict__ offsets,
        const int* __restrict__ classIdx,
        const float* __restrict__ neg_sum,
        float* __restrict__ total, unsigned* __restrict__ done,
        float* __restrict__ out) {
    __shared__ __attribute__((aligned(16))) unsigned short s_feat[MAXR * 128]; // 48 KB
    __shared__ int s_rows[MAXR];
    __shared__ float s_ns[MAXR];
    __shared__ float red[4];

    int c = blockIdx.x;
    int m = counts[c], off = offsets[c];
    int twoM = 2 * m; if (twoM > MAXR) twoM = MAXR;
    int tid = threadIdx.x, wave = tid >> 6, lane = tid & 63;
    int q = lane >> 4, nq = lane & 15;

    for (int r = tid; r < twoM; r += 256) {
        int b = classIdx[off + (r < m ? r : r - m)];
        int row = (r < m) ? b : b + BATCH;
        s_rows[r] = row;
        s_ns[r] = neg_sum[row];
    }
    __syncthreads();

    int ntile = (twoM + 63) >> 6;            // 1..3
    int nchunk = ntile * 64 * 16;
    for (int widx = wave; widx * 64 < nchunk; widx += 4) {
        int chunkIdx = widx * 64 + lane;
        int r = chunkIdx >> 4, cS = chunkIdx & 15;
        int cG = cS ^ (r & 15);
        int rc = r < twoM ? r : twoM - 1;
        const unsigned short* gp = nf + (size_t)s_rows[rc] * DD + cG * 8;
        unsigned short* lp = s_feat + (size_t)widx * 512;
        __builtin_amdgcn_global_load_lds(
            (const __attribute__((address_space(1))) void*)gp,
            (__attribute__((address_space(3))) void*)lp, 16, 0, 0);
    }
    __syncthreads();

    const char* sB = (const char*)s_feat;
    float partial = 0.0f;
    int npairs = ntile * ntile;
    for (int pp = wave; pp < npairs; pp += 4) {
        int ti = pp / ntile, tj = pp - ti * ntile;
        bf16x8 aF[4][4];
        #pragma unroll
        for (int rs = 0; rs < 4; ++rs) {
            int rA = ti * 64 + rs * 16 + nq;
            #pragma unroll
            for (int s = 0; s < 4; ++s) {
                int slot = rA * 16 + ((s * 4 + q) ^ nq);
                aF[rs][s] = *(const bf16x8*)(sB + slot * 16);
            }
        }
        f32x4 acc[4][4];
        #pragma unroll
        for (int rs = 0; rs < 4; ++rs)
            #pragma unroll
            for (int cs = 0; cs < 4; ++cs) acc[rs][cs] = (f32x4){0.f, 0.f, 0.f, 0.f};
        #pragma unroll
        for (int s = 0; s < 4; ++s) {
            bf16x8 bF[4];
            #pragma unroll
            for (int cs = 0; cs < 4; ++cs) {
                int rB = tj * 64 + cs * 16 + nq;
                int slot = rB * 16 + ((s * 4 + q) ^ nq);
                bF[cs] = *(const bf16x8*)(sB + slot * 16);
            }
            #pragma unroll
            for (int rs = 0; rs < 4; ++rs)
                #pragma unroll
                for (int cs = 0; cs < 4; ++cs)
                    acc[rs][cs] = __builtin_amdgcn_mfma_f32_16x16x32_bf16(
                        aF[rs][s], bF[cs], acc[rs][cs], 0, 0, 0);
        }
        #pragma unroll
        for (int cs = 0; cs < 4; ++cs) {
            int qq = tj * 64 + cs * 16 + nq;
            float ns = s_ns[qq < twoM ? qq : 0];
            #pragma unroll
            for (int rs = 0; rs < 4; ++rs)
                #pragma unroll
                for (int rr = 0; rr < 4; ++rr) {
                    int p = ti * 64 + rs * 16 + q * 4 + rr;
                    bool valid = (p < twoM) && (qq < twoM) && (p != qq);
                    float logit = acc[rs][cs][rr] * SCALE;
                    float term = logit - __logf(ns + __expf(logit));
                    partial += valid ? term : 0.0f;
                }
        }
    }
    #pragma unroll
    for (int mm = 32; mm >= 1; mm >>= 1) partial += __shfl_xor(partial, mm, 64);
    if (lane == 0) red[wave] = partial;
    __syncthreads();
    if (tid == 0) {
        atomicAdd(total, red[0] + red[1] + red[2] + red[3]);
        __threadfence();
        unsigned prev = __hip_atomic_fetch_add(done, 1u, __ATOMIC_ACQ_REL,
                                               __HIP_MEMORY_SCOPE_AGENT);
        if (prev == (unsigned)(NCLS - 1)) {
            float tot = __hip_atomic_load(total, __ATOMIC_ACQUIRE,
                                          __HIP_MEMORY_SCOPE_AGENT);
            out[0] = -tot * (1.0f / (float)NN);
        }
    }
}

extern "C" void kernel_launch(void* const* d_in, const int* in_sizes, int n_in,
                              void* d_out, int out_size, void* d_ws, size_t ws_size,
                              hipStream_t stream) {
    const float* feat = (const float*)d_in[0];
    const int* labels = (const int*)d_in[1];
    unsigned short* nf  = (unsigned short*)d_ws;
    unsigned short* nfA = nf + (size_t)NN * DD;
    float* neg_sum = (float*)(nfA + (size_t)NN * DD);
    float* total    = neg_sum + NN;           // 1
    unsigned* done  = (unsigned*)(total + 1); // 1
    int* counts     = (int*)(done + 1);       // 100
    int* offsets    = counts + NCLS;          // 101
    int* classIdx   = offsets + NCLS + 1;     // 4096
    float* out = (float*)d_out;

    hipLaunchKernelGGL(k_normalize, dim3(NN / 4), dim3(256), 0, stream,
                       feat, nf, nfA, neg_sum, labels, counts, offsets, classIdx);
    hipLaunchKernelGGL(k_negsum, dim3(32, 32), dim3(256), 0, stream, nfA, labels, neg_sum);
    hipLaunchKernelGGL(k_loss, dim3(NCLS), dim3(256), 0, stream,
                       nf, counts, offsets, classIdx, neg_sum, total, done, out);
}